// Round 3
// baseline (688.721 us; speedup 1.0000x reference)
//
#include <hip/hip_runtime.h>

// Output layout (floats): [0]=loss, [1..8388608]=quantized BCHW,
// [8388609]=perplexity, [8388610..]=encodings (N x K)
#define QUANT_OFF 1
#define PERP_OFF 8388609
#define ENC_OFF  8388610

// ws layout: [0,2048) counts u32[512]; [2048,2052) float loss accum;
//            [4096,6144) sw2 float[512]

__global__ void vq_prep(const float* __restrict__ W, float* __restrict__ sw2) {
  int k = blockIdx.x;     // 512 blocks
  int d = threadIdx.x;    // 64 threads
  float wd = W[k * 64 + d];
  float s = wd * wd;
  #pragma unroll
  for (int off = 32; off; off >>= 1) s += __shfl_down(s, off, 64);
  if (d == 0) sw2[k] = s;
}

// Block = 256 threads = 64 points x 4 K-teams. Wave t scans codes
// [128t, 128t+128). Grid = 2048 blocks -> ~8 blocks/CU.
__global__ __launch_bounds__(256, 5) void vq_main(
    const float* __restrict__ x, const float* __restrict__ W,
    const float* __restrict__ sw2, float* __restrict__ enc,
    float* __restrict__ quant, unsigned int* __restrict__ counts,
    float* __restrict__ accum) {
  __shared__ float sbest[256];
  __shared__ int   sbi[256];
  __shared__ int   wbi[64];
  __shared__ unsigned int hcnt[512];

  int tid = threadIdx.x;
  int p   = tid & 63;        // point in block (== lane)
  int t   = tid >> 6;        // K-team (== wave)
  int n0  = blockIdx.x * 64;
  int n   = n0 + p;
  int b   = n >> 12;         // 64 consecutive points never cross a batch
  int hwp = n & 4095;
  const float* xp = x + b * 262144 + hwp;   // channel stride 4096 floats

  hcnt[tid] = 0u;
  hcnt[tid + 256] = 0u;

  // Point's 64 channels -> VGPRs (coalesced: lanes = consecutive hw)
  float xv[64];
  float cn = 0.0f;
  #pragma unroll
  for (int c = 0; c < 64; ++c) {
    float v = xp[c * 4096];
    xv[c] = v;
    cn = fmaf(v, v, cn);
  }

  float best = 3.4e38f;
  int bi = 0;
  const float* Wt   = W + (t << 13);    // team's 128 rows
  const float* sw2t = sw2 + (t << 7);
  for (int k = 0; k < 128; k += 2) {
    const float* w0 = Wt + (k << 6);
    const float* w1 = w0 + 64;
    float a0 = 0.f, a1 = 0.f, a2 = 0.f, a3 = 0.f;
    float c0 = 0.f, c1 = 0.f, c2 = 0.f, c3 = 0.f;
    #pragma unroll
    for (int d = 0; d < 64; d += 4) {
      a0 = fmaf(xv[d + 0], w0[d + 0], a0);
      a1 = fmaf(xv[d + 1], w0[d + 1], a1);
      a2 = fmaf(xv[d + 2], w0[d + 2], a2);
      a3 = fmaf(xv[d + 3], w0[d + 3], a3);
      c0 = fmaf(xv[d + 0], w1[d + 0], c0);
      c1 = fmaf(xv[d + 1], w1[d + 1], c1);
      c2 = fmaf(xv[d + 2], w1[d + 2], c2);
      c3 = fmaf(xv[d + 3], w1[d + 3], c3);
    }
    float s0 = sw2t[k]     - 2.0f * ((a0 + a1) + (a2 + a3));
    float s1 = sw2t[k + 1] - 2.0f * ((c0 + c1) + (c2 + c3));
    if (s0 < best) { best = s0; bi = (t << 7) + k; }
    if (s1 < best) { best = s1; bi = (t << 7) + k + 1; }
  }
  sbest[tid] = best;
  sbi[tid]   = bi;
  __syncthreads();

  // Combine the 4 team partials (team order => lowest-index tie rule)
  if (tid < 64) {
    float bb = sbest[tid];
    int  bbi = sbi[tid];
    #pragma unroll
    for (int q = 1; q < 4; ++q) {
      float v  = sbest[(q << 6) + tid];
      int   vi = sbi[(q << 6) + tid];
      if (v < bb) { bb = v; bbi = vi; }
    }
    wbi[tid] = bbi;
    atomicAdd(&hcnt[bbi], 1u);
    float dl = cn + bb;     // ||x||^2 + (||w||^2 - 2 x.w)
    #pragma unroll
    for (int off = 32; off; off >>= 1) dl += __shfl_down(dl, off, 64);
    if (tid == 0) atomicAdd(accum, dl);
  }
  __syncthreads();

  // flush histogram (combine atomics complete before the sync above)
  unsigned int v0 = hcnt[tid], v1 = hcnt[tid + 256];
  if (v0) atomicAdd(&counts[tid], v0);
  if (v1) atomicAdd(&counts[tid + 256], v1);

  // quantized BCHW: lane p stores channels [16t, 16t+16) for its point
  {
    int bip = wbi[p];
    const float4* wrow = (const float4*)(W + (bip << 6) + (t << 4));
    float* qp = quant + b * 262144 + (t << 4) * 4096 + hwp;
    #pragma unroll
    for (int q4 = 0; q4 < 4; ++q4) {
      float4 wv = wrow[q4];
      qp[(q4 * 4 + 0) * 4096] = wv.x;
      qp[(q4 * 4 + 1) * 4096] = wv.y;
      qp[(q4 * 4 + 2) * 4096] = wv.z;
      qp[(q4 * 4 + 3) * 4096] = wv.w;
    }
  }

  // one-hot rows: wave t writes points [16t, 16t+16); bi is an LDS
  // broadcast (uniform per row) -> no shuffles, float4 stores
  {
    #pragma unroll
    for (int j = 0; j < 16; ++j) {
      int pp = (t << 4) + j;
      int rb = wbi[pp];
      float* rowp = enc + (long long)(n0 + pp) * 512 + p * 8;
      int base = p * 8;
      float4 u, w;
      u.x = (base + 0 == rb) ? 1.0f : 0.0f;
      u.y = (base + 1 == rb) ? 1.0f : 0.0f;
      u.z = (base + 2 == rb) ? 1.0f : 0.0f;
      u.w = (base + 3 == rb) ? 1.0f : 0.0f;
      w.x = (base + 4 == rb) ? 1.0f : 0.0f;
      w.y = (base + 5 == rb) ? 1.0f : 0.0f;
      w.z = (base + 6 == rb) ? 1.0f : 0.0f;
      w.w = (base + 7 == rb) ? 1.0f : 0.0f;
      ((float4*)rowp)[0] = u;
      ((float4*)rowp)[1] = w;
    }
  }
}

__global__ void vq_final(const unsigned int* __restrict__ counts,
                         const float* __restrict__ accum,
                         float* __restrict__ out) {
  __shared__ float red[8];
  int k = threadIdx.x;  // 512 threads
  float pr = (float)counts[k] * (1.0f / 131072.0f);
  float s = pr * logf(pr + 1e-10f);
  #pragma unroll
  for (int off = 32; off; off >>= 1) s += __shfl_down(s, off, 64);
  if ((k & 63) == 0) red[k >> 6] = s;
  __syncthreads();
  if (k == 0) {
    float H = 0.0f;
    #pragma unroll
    for (int i = 0; i < 8; ++i) H += red[i];
    out[PERP_OFF] = expf(-H);
    out[0] = 1.25f * accum[0] * (1.0f / 8388608.0f);
  }
}

extern "C" void kernel_launch(void* const* d_in, const int* in_sizes, int n_in,
                              void* d_out, int out_size, void* d_ws, size_t ws_size,
                              hipStream_t stream) {
  const float* x = (const float*)d_in[0];
  const float* W = (const float*)d_in[1];
  float* out   = (float*)d_out;
  float* quant = out + QUANT_OFF;
  float* enc   = out + ENC_OFF;

  char* ws = (char*)d_ws;
  unsigned int* counts = (unsigned int*)ws;
  float* accum         = (float*)(ws + 2048);
  float* sw2           = (float*)(ws + 4096);

  hipMemsetAsync(ws, 0, 4096, stream);
  vq_prep<<<512, 64, 0, stream>>>(W, sw2);
  vq_main<<<2048, 256, 0, stream>>>(x, W, sw2, enc, quant, counts, accum);
  vq_final<<<1, 512, 0, stream>>>(counts, accum, out);
}

// Round 4
// 346.235 us; speedup vs baseline: 1.9892x; 1.9892x over previous
//
#include <hip/hip_runtime.h>

// Output layout (floats): [0]=loss, [1..8388608]=quantized BCHW,
// [8388609]=perplexity, [8388610..]=encodings (N x K)
#define QUANT_OFF 1
#define PERP_OFF 8388609
#define ENC_OFF  8388610

// ws: [0,2048) counts u32[512]; [2048,2052) loss accum f32; [4096,6144) sw2 f32[512]

__global__ void vq_prep(const float* __restrict__ W, float* __restrict__ sw2) {
  int k = blockIdx.x;     // 512 blocks
  int d = threadIdx.x;    // 64 threads
  float wd = W[k * 64 + d];
  float s = wd * wd;
  #pragma unroll
  for (int off = 32; off; off >>= 1) s += __shfl_down(s, off, 64);
  if (d == 0) sw2[k] = s;
}

// Block = 256 threads = 256 points (1 pt/thread), each scans all 512 codes.
// W flows through LDS in 64-code chunks, double-buffered, reg-staged.
// The 268MB one-hot zero-fill is interleaved with compute (64-col stripes).
__global__ __launch_bounds__(256) void vq_main(
    const float* __restrict__ x, const float* __restrict__ W,
    const float* __restrict__ sw2g, float* __restrict__ enc,
    float* __restrict__ quant, unsigned int* __restrict__ counts,
    float* __restrict__ accum) {
  __shared__ float wbuf[2][4160];   // 64 codes x 64 dims + 64 sw2, x2 buffers
  __shared__ unsigned int hcnt[512];
  __shared__ float lred[4];

  int tid = threadIdx.x;
  int n0  = blockIdx.x << 8;
  int n   = n0 + tid;
  int b   = n >> 12;               // 256-point blocks never cross a batch
  int hwp = n & 4095;
  const float* xp = x + b * 262144 + hwp;   // channel stride 4096 floats

  // x gather first: 64 coalesced dword loads, latency hides under staging
  float xv[64];
  float cn = 0.0f;
  #pragma unroll
  for (int c = 0; c < 64; ++c) {
    float v = xp[c * 4096];
    xv[c] = v;
    cn = fmaf(v, v, cn);
  }

  hcnt[tid] = 0u;
  hcnt[tid + 256] = 0u;

  // prologue: stage chunk 0 (16KB W + 64 sw2)
  {
    const float4* g = (const float4*)W;
    float4 t0 = g[tid], t1 = g[tid + 256], t2 = g[tid + 512], t3 = g[tid + 768];
    float s2v = (tid < 64) ? sw2g[tid] : 0.0f;
    *(float4*)&wbuf[0][(tid) * 4]       = t0;
    *(float4*)&wbuf[0][(tid + 256) * 4] = t1;
    *(float4*)&wbuf[0][(tid + 512) * 4] = t2;
    *(float4*)&wbuf[0][(tid + 768) * 4] = t3;
    if (tid < 64) wbuf[0][4096 + tid] = s2v;
  }
  __syncthreads();

  float best = 3.4e38f;
  int bi = 0;

  for (int j = 0; j < 8; ++j) {
    int cur = j & 1;
    // T14: issue next chunk's global loads EARLY
    float4 t0, t1, t2, t3; float s2v = 0.0f;
    if (j < 7) {
      const float4* g = (const float4*)(W + ((j + 1) << 12));
      t0 = g[tid]; t1 = g[tid + 256]; t2 = g[tid + 512]; t3 = g[tid + 768];
      if (tid < 64) s2v = sw2g[((j + 1) << 6) + tid];
    }

    // zero stripe for this chunk's 64 columns (coalesced, fire-and-forget)
    {
      float4 z = make_float4(0.f, 0.f, 0.f, 0.f);
      #pragma unroll
      for (int i = 0; i < 16; ++i) {
        int idx4 = (i << 8) + tid;          // dwordx4 index in 256x64 stripe
        int row  = idx4 >> 4;
        int colq = idx4 & 15;
        *(float4*)(enc + ((long long)(n0 + row) << 9) + (j << 6) + (colq << 2)) = z;
      }
    }

    // compute chunk j from LDS (broadcast ds_read_b128, fine-grain lgkmcnt)
    const float* wc  = &wbuf[cur][0];
    const float* s2c = &wbuf[cur][4096];
    for (int k = 0; k < 64; k += 2) {
      const float* w0 = wc + (k << 6);
      const float* w1 = w0 + 64;
      float a0 = 0.f, a1 = 0.f, a2 = 0.f, a3 = 0.f;
      float c0 = 0.f, c1 = 0.f, c2 = 0.f, c3 = 0.f;
      #pragma unroll
      for (int d = 0; d < 64; d += 4) {
        float4 u = *(const float4*)(w0 + d);
        float4 v = *(const float4*)(w1 + d);
        a0 = fmaf(xv[d + 0], u.x, a0);
        a1 = fmaf(xv[d + 1], u.y, a1);
        a2 = fmaf(xv[d + 2], u.z, a2);
        a3 = fmaf(xv[d + 3], u.w, a3);
        c0 = fmaf(xv[d + 0], v.x, c0);
        c1 = fmaf(xv[d + 1], v.y, c1);
        c2 = fmaf(xv[d + 2], v.z, c2);
        c3 = fmaf(xv[d + 3], v.w, c3);
      }
      float s0 = s2c[k]     - 2.0f * ((a0 + a1) + (a2 + a3));
      float s1 = s2c[k + 1] - 2.0f * ((c0 + c1) + (c2 + c3));
      if (s0 < best) { best = s0; bi = (j << 6) + k; }
      if (s1 < best) { best = s1; bi = (j << 6) + k + 1; }
    }

    // T14: write staged regs to the other LDS buffer late
    if (j < 7) {
      int nxt = cur ^ 1;
      *(float4*)&wbuf[nxt][(tid) * 4]       = t0;
      *(float4*)&wbuf[nxt][(tid + 256) * 4] = t1;
      *(float4*)&wbuf[nxt][(tid + 512) * 4] = t2;
      *(float4*)&wbuf[nxt][(tid + 768) * 4] = t3;
      if (tid < 64) wbuf[nxt][4096 + tid] = s2v;
    }
    __syncthreads();   // compiler emits vmcnt(0)+lgkmcnt(0) drain here
  }
  // After the last barrier: all zero-stores (incl. other threads') retired.

  // the single 1.0 per row
  enc[((long long)n << 9) + bi] = 1.0f;

  // quantized BCHW: gather code row (L2-hot), strided coalesced stores
  {
    const float4* wr = (const float4*)(W + (bi << 6));
    float* qp = quant + b * 262144 + hwp;
    #pragma unroll
    for (int q4 = 0; q4 < 16; ++q4) {
      float4 wv = wr[q4];
      qp[(q4 * 4 + 0) * 4096] = wv.x;
      qp[(q4 * 4 + 1) * 4096] = wv.y;
      qp[(q4 * 4 + 2) * 4096] = wv.z;
      qp[(q4 * 4 + 3) * 4096] = wv.w;
    }
  }

  // histogram + loss
  atomicAdd(&hcnt[bi], 1u);
  float dl = cn + best;   // ||x||^2 + (||w||^2 - 2 x.w) = min squared dist
  #pragma unroll
  for (int off = 32; off; off >>= 1) dl += __shfl_down(dl, off, 64);
  if ((tid & 63) == 0) lred[tid >> 6] = dl;
  __syncthreads();
  if (tid == 0) atomicAdd(accum, (lred[0] + lred[1]) + (lred[2] + lred[3]));

  unsigned int v0 = hcnt[tid], v1 = hcnt[tid + 256];
  if (v0) atomicAdd(&counts[tid], v0);
  if (v1) atomicAdd(&counts[tid + 256], v1);
}

__global__ void vq_final(const unsigned int* __restrict__ counts,
                         const float* __restrict__ accum,
                         float* __restrict__ out) {
  __shared__ float red[8];
  int k = threadIdx.x;  // 512 threads
  float pr = (float)counts[k] * (1.0f / 131072.0f);
  float s = pr * logf(pr + 1e-10f);
  #pragma unroll
  for (int off = 32; off; off >>= 1) s += __shfl_down(s, off, 64);
  if ((k & 63) == 0) red[k >> 6] = s;
  __syncthreads();
  if (k == 0) {
    float H = 0.0f;
    #pragma unroll
    for (int i = 0; i < 8; ++i) H += red[i];
    out[PERP_OFF] = expf(-H);
    out[0] = 1.25f * accum[0] * (1.0f / 8388608.0f);
  }
}

extern "C" void kernel_launch(void* const* d_in, const int* in_sizes, int n_in,
                              void* d_out, int out_size, void* d_ws, size_t ws_size,
                              hipStream_t stream) {
  (void)in_sizes; (void)n_in; (void)out_size; (void)ws_size;
  const float* x = (const float*)d_in[0];
  const float* W = (const float*)d_in[1];
  float* out   = (float*)d_out;
  float* quant = out + QUANT_OFF;
  float* enc   = out + ENC_OFF;

  char* ws = (char*)d_ws;
  unsigned int* counts = (unsigned int*)ws;
  float* accum         = (float*)(ws + 2048);
  float* sw2           = (float*)(ws + 4096);

  hipMemsetAsync(ws, 0, 4096, stream);
  vq_prep<<<512, 64, 0, stream>>>(W, sw2);
  vq_main<<<512, 256, 0, stream>>>(x, W, sw2, enc, quant, counts, accum);
  vq_final<<<1, 512, 0, stream>>>(counts, accum, out);
}

// Round 5
// 178.590 us; speedup vs baseline: 3.8564x; 1.9387x over previous
//
#include <hip/hip_runtime.h>

// Output layout (floats): [0]=loss, [1..8388608]=quantized BCHW,
// [8388609]=perplexity, [8388610..]=encodings (N x K)
#define QUANT_OFF 1
#define PERP_OFF 8388609
#define ENC_OFF  8388610

// ws: [0,2048) counts u32[512]; [2048,2052) loss accum f32; [4096,6144) sw2 f32[512]

typedef __attribute__((ext_vector_type(8))) short bf16x8;
typedef __attribute__((ext_vector_type(4))) float f32x4;

__device__ __forceinline__ unsigned short f2bf(float f) {
  unsigned int u = __float_as_uint(f);
  u += 0x7fffu + ((u >> 16) & 1u);
  return (unsigned short)(u >> 16);
}

__global__ void vq_prep(const float* __restrict__ W, float* __restrict__ sw2) {
  int k = blockIdx.x;     // 512 blocks
  int d = threadIdx.x;    // 64 threads
  float wd = W[k * 64 + d];
  float s = wd * wd;
  #pragma unroll
  for (int off = 32; off; off >>= 1) s += __shfl_down(s, off, 64);
  if (d == 0) sw2[k] = s;
}

// 512 thr = 8 waves; wave owns 16 points; block = 128 points; grid = 1024.
// score[k] = sw2[k] + x . (-2 W[k]) via mfma_16x16x32_bf16 with C-init = sw2.
// D[code_row, point_col]: col = lane&15 (point), row = (lane>>4)*4 + reg.
__global__ __launch_bounds__(512) void vq_main(
    const float* __restrict__ x, const float* __restrict__ W,
    const float* __restrict__ sw2g, float* __restrict__ enc,
    float* __restrict__ quant, unsigned int* __restrict__ counts,
    float* __restrict__ accum) {
  __shared__ unsigned short wlds[32768];  // 512 rows x 64 bf16 of (-2W), XOR-swizzled
  __shared__ float sw2s[512];
  __shared__ unsigned int hcnt[512];

  int tid  = threadIdx.x;
  int lane = tid & 63;
  int wv   = tid >> 6;
  int rl   = lane & 15;        // point-in-wave / code-row-in-tile
  int g    = lane >> 4;        // k-group (8 dims) / code-row-group
  int n0   = (blockIdx.x << 7) + (wv << 4);   // wave's first point
  int b    = n0 >> 12;         // 128-pt blocks never cross a batch
  int hw0  = n0 & 4095;
  const float* xb = x + b * 262144 + hw0 + rl;   // channel stride 4096

  hcnt[tid] = 0u;

  // ---- x: 16 dims per lane (dims g*8+e+32s of point rl), 4x64B segments/load
  float xr[16];
  #pragma unroll
  for (int s = 0; s < 2; ++s)
    #pragma unroll
    for (int e = 0; e < 8; ++e)
      xr[s * 8 + e] = xb[(g * 8 + e + 32 * s) * 4096];

  // ---- stage -2W as bf16 into swizzled LDS (unit = 16B = 8 bf16)
  #pragma unroll
  for (int i = 0; i < 8; ++i) {
    int u = (i << 9) + tid;          // 4096 units
    int r = u >> 3, c = u & 7;
    const float4* gsrc = (const float4*)(W + u * 8);
    float4 lo = gsrc[0], hi = gsrc[1];
    bf16x8 v;
    v[0] = f2bf(-2.0f * lo.x); v[1] = f2bf(-2.0f * lo.y);
    v[2] = f2bf(-2.0f * lo.z); v[3] = f2bf(-2.0f * lo.w);
    v[4] = f2bf(-2.0f * hi.x); v[5] = f2bf(-2.0f * hi.y);
    v[6] = f2bf(-2.0f * hi.z); v[7] = f2bf(-2.0f * hi.w);
    *(bf16x8*)&wlds[r * 64 + ((c ^ (r & 7)) << 3)] = v;
  }
  sw2s[tid < 512 ? tid : 0] = sw2g[tid < 512 ? tid : 0];

  // ---- B-frags (x as bf16) + ||x||^2 partial
  float cnp = 0.0f;
  bf16x8 xf0, xf1;
  #pragma unroll
  for (int e = 0; e < 8; ++e) {
    xf0[e] = f2bf(xr[e]);     cnp = fmaf(xr[e], xr[e], cnp);
    xf1[e] = f2bf(xr[8 + e]); cnp = fmaf(xr[8 + e], xr[8 + e], cnp);
  }
  float cn = cnp + __shfl_xor(cnp, 16);
  cn += __shfl_xor(cn, 32);    // all lanes: full ||x||^2 of point rl

  __syncthreads();

  // ---- 32 code-tiles: 2 MFMA each, idx packed into low 9 mantissa bits
  float best = __uint_as_float(0x7f7fffffu);
  int swz = rl & 7;
  int c0 = (g ^ swz) << 3;         // kstep 0 chunk (ushort offset)
  int c1 = ((4 + g) ^ swz) << 3;   // kstep 1 chunk
  int rowbase = rl * 64;           // row&7 == rl&7 (tiles stride 16)
  #pragma unroll
  for (int t = 0; t < 32; ++t) {
    f32x4 acc = *(const f32x4*)&sw2s[t * 16 + g * 4];
    bf16x8 a0 = *(const bf16x8*)&wlds[t * 1024 + rowbase + c0];
    bf16x8 a1 = *(const bf16x8*)&wlds[t * 1024 + rowbase + c1];
    acc = __builtin_amdgcn_mfma_f32_16x16x32_bf16(a0, xf0, acc, 0, 0, 0);
    acc = __builtin_amdgcn_mfma_f32_16x16x32_bf16(a1, xf1, acc, 0, 0, 0);
    #pragma unroll
    for (int j = 0; j < 4; ++j) {
      unsigned int pk = (__float_as_uint(acc[j]) & ~511u) | (t * 16 + g * 4 + j);
      best = fminf(best, __uint_as_float(pk));
    }
  }
  best = fminf(best, __shfl_xor(best, 16));
  best = fminf(best, __shfl_xor(best, 32));
  int bi = __float_as_uint(best) & 511;                          // argmin code
  float score = __uint_as_float(__float_as_uint(best) & ~511u);  // ~exact score

  // ---- loss: all 64 lanes hold (cn+score) of point lane&15 -> sum = 4x
  float dl = cn + score;
  #pragma unroll
  for (int off = 1; off < 64; off <<= 1) dl += __shfl_xor(dl, off);
  if (lane == 0) atomicAdd(accum, dl * 0.25f);

  if (lane < 16) atomicAdd(&hcnt[bi], 1u);

  // ---- quantized BCHW (exact f32 from global W, L2-hot gathers)
  {
    float* qp = quant + b * 262144 + hw0 + rl;
    const float* wrow = W + (bi << 6);
    #pragma unroll
    for (int i = 0; i < 16; ++i) {
      int c = i * 4 + g;
      qp[c * 4096] = wrow[c];
    }
  }

  // ---- one-hot rows: 2 float4 stores per row, 1.0 folded into the fill
  {
    float* ebase = enc + (long long)n0 * 512;
    for (int r = 0; r < 16; ++r) {
      int rb = __shfl(bi, r);           // wave-uniform
      int schunk = rb >> 2, slot = rb & 3;
      float4 pat;
      pat.x = (slot == 0) ? 1.0f : 0.0f;
      pat.y = (slot == 1) ? 1.0f : 0.0f;
      pat.z = (slot == 2) ? 1.0f : 0.0f;
      pat.w = (slot == 3) ? 1.0f : 0.0f;
      float4 z = make_float4(0.f, 0.f, 0.f, 0.f);
      float4* rowp = (float4*)(ebase + (long long)r * 512);
      rowp[lane]      = (lane == schunk)      ? pat : z;
      rowp[lane + 64] = (lane + 64 == schunk) ? pat : z;
    }
  }

  // ---- histogram flush
  __syncthreads();
  unsigned int hv = hcnt[tid];
  if (hv) atomicAdd(&counts[tid], hv);
}

__global__ void vq_final(const unsigned int* __restrict__ counts,
                         const float* __restrict__ accum,
                         float* __restrict__ out) {
  __shared__ float red[8];
  int k = threadIdx.x;  // 512 threads
  float pr = (float)counts[k] * (1.0f / 131072.0f);
  float s = pr * logf(pr + 1e-10f);
  #pragma unroll
  for (int off = 32; off; off >>= 1) s += __shfl_down(s, off, 64);
  if ((k & 63) == 0) red[k >> 6] = s;
  __syncthreads();
  if (k == 0) {
    float H = 0.0f;
    #pragma unroll
    for (int i = 0; i < 8; ++i) H += red[i];
    out[PERP_OFF] = expf(-H);
    out[0] = 1.25f * accum[0] * (1.0f / 8388608.0f);
  }
}

extern "C" void kernel_launch(void* const* d_in, const int* in_sizes, int n_in,
                              void* d_out, int out_size, void* d_ws, size_t ws_size,
                              hipStream_t stream) {
  (void)in_sizes; (void)n_in; (void)out_size; (void)ws_size;
  const float* x = (const float*)d_in[0];
  const float* W = (const float*)d_in[1];
  float* out   = (float*)d_out;
  float* quant = out + QUANT_OFF;
  float* enc   = out + ENC_OFF;

  char* ws = (char*)d_ws;
  unsigned int* counts = (unsigned int*)ws;
  float* accum         = (float*)(ws + 2048);
  float* sw2           = (float*)(ws + 4096);

  hipMemsetAsync(ws, 0, 4096, stream);
  vq_prep<<<512, 64, 0, stream>>>(W, sw2);
  vq_main<<<1024, 512, 0, stream>>>(x, W, sw2, enc, quant, counts, accum);
  vq_final<<<1, 512, 0, stream>>>(counts, accum, out);
}

// Round 6
// 163.163 us; speedup vs baseline: 4.2211x; 1.0946x over previous
//
#include <hip/hip_runtime.h>

// Output layout (floats): [0]=loss, [1..8388608]=quantized BCHW,
// [8389609... see defines below
#define QUANT_OFF 1
#define PERP_OFF 8388609
#define ENC_OFF  8388610

// ws: [0,2048)    counts u32[512]
//     [2048,4096) sw2 f32[512]
//     [4096,8192) loss partials f32[1024]
//     [8192,73728)   w2 bf16[512*64]  (-2W)
//     [73728,335872) idx u16[131072]

typedef __attribute__((ext_vector_type(8))) short bf16x8;
typedef __attribute__((ext_vector_type(2))) float f32x2;
typedef __attribute__((ext_vector_type(4))) float f32x4;

__device__ __forceinline__ unsigned short f2bf(float f) {
  unsigned int u = __float_as_uint(f);
  u += 0x7fffu + ((u >> 16) & 1u);
  return (unsigned short)(u >> 16);
}

__global__ void vq_prep(const float* __restrict__ W, float* __restrict__ sw2,
                        unsigned short* __restrict__ w2) {
  int k = blockIdx.x;     // 512 blocks
  int d = threadIdx.x;    // 64 threads
  float wd = W[k * 64 + d];
  w2[k * 64 + d] = f2bf(-2.0f * wd);
  float s = wd * wd;
  #pragma unroll
  for (int off = 32; off; off >>= 1) s += __shfl_down(s, off, 64);
  if (d == 0) sw2[k] = s;
}

// 512 thr = 8 waves; wave owns 16 points; block = 128 points; grid = 1024.
// score[k] = sw2[k] + x . (-2 W[k]) via mfma_16x16x32_bf16 with C-init = sw2.
// Compute only: writes idx (u16/pt), per-block loss partial, histogram.
__global__ __launch_bounds__(512) void vq_argmin(
    const float* __restrict__ x, const unsigned short* __restrict__ w2,
    const float* __restrict__ sw2g, unsigned short* __restrict__ idx,
    unsigned int* __restrict__ counts, float* __restrict__ lpart) {
  __shared__ unsigned short wlds[32768];  // 512 x 64 bf16 (-2W), XOR-swizzled
  __shared__ float sw2s[512];
  __shared__ unsigned int hcnt[512];
  __shared__ float lred[8];

  int tid  = threadIdx.x;
  int lane = tid & 63;
  int wv   = tid >> 6;
  int rl   = lane & 15;        // point-in-wave / code-row-in-tile
  int g    = lane >> 4;        // k-group (8 dims) / code-row-group
  int n0   = (blockIdx.x << 7) + (wv << 4);   // wave's first point
  int b    = n0 >> 12;         // 128-pt blocks never cross a batch
  int hw0  = n0 & 4095;
  const float* xb = x + b * 262144 + hw0 + rl;   // channel stride 4096

  hcnt[tid] = 0u;
  sw2s[tid] = sw2g[tid];

  // x: 16 dims per lane (dims g*8+e+32s of point rl)
  float xr[16];
  #pragma unroll
  for (int s = 0; s < 2; ++s)
    #pragma unroll
    for (int e = 0; e < 8; ++e)
      xr[s * 8 + e] = xb[(g * 8 + e + 32 * s) * 4096];

  // stage pre-packed bf16 W into swizzled LDS (unit = 16B = 8 bf16)
  #pragma unroll
  for (int i = 0; i < 8; ++i) {
    int u = (i << 9) + tid;          // 4096 units
    int r = u >> 3, c = u & 7;
    bf16x8 v = *(const bf16x8*)&w2[u * 8];
    *(bf16x8*)&wlds[r * 64 + ((c ^ (r & 7)) << 3)] = v;
  }

  // B-frags + ||x||^2
  float cnp = 0.0f;
  bf16x8 xf0, xf1;
  #pragma unroll
  for (int e = 0; e < 8; ++e) {
    xf0[e] = f2bf(xr[e]);     cnp = fmaf(xr[e], xr[e], cnp);
    xf1[e] = f2bf(xr[8 + e]); cnp = fmaf(xr[8 + e], xr[8 + e], cnp);
  }
  float cn = cnp + __shfl_xor(cnp, 16);
  cn += __shfl_xor(cn, 32);

  __syncthreads();

  // 32 code-tiles: 2 MFMA each; idx packed into low 9 mantissa bits
  float best = __uint_as_float(0x7f7fffffu);
  int swz = rl & 7;
  int c0 = (g ^ swz) << 3;
  int c1 = ((4 + g) ^ swz) << 3;
  int rowbase = rl * 64;
  #pragma unroll
  for (int t = 0; t < 32; ++t) {
    f32x4 acc = *(const f32x4*)&sw2s[t * 16 + g * 4];
    bf16x8 a0 = *(const bf16x8*)&wlds[t * 1024 + rowbase + c0];
    bf16x8 a1 = *(const bf16x8*)&wlds[t * 1024 + rowbase + c1];
    acc = __builtin_amdgcn_mfma_f32_16x16x32_bf16(a0, xf0, acc, 0, 0, 0);
    acc = __builtin_amdgcn_mfma_f32_16x16x32_bf16(a1, xf1, acc, 0, 0, 0);
    #pragma unroll
    for (int j = 0; j < 4; ++j) {
      unsigned int pk = (__float_as_uint(acc[j]) & ~511u) | (t * 16 + g * 4 + j);
      best = fminf(best, __uint_as_float(pk));
    }
  }
  best = fminf(best, __shfl_xor(best, 16));
  best = fminf(best, __shfl_xor(best, 32));
  int bi = __float_as_uint(best) & 511;
  float score = __uint_as_float(__float_as_uint(best) & ~511u);

  if (lane < 16) {
    idx[n0 + lane] = (unsigned short)bi;
    atomicAdd(&hcnt[bi], 1u);
  }

  // loss: 4 copies per point across the wave -> sum * 0.25
  float dl = cn + score;
  #pragma unroll
  for (int off = 1; off < 64; off <<= 1) dl += __shfl_xor(dl, off);
  if (lane == 0) lred[wv] = dl * 0.25f;

  __syncthreads();
  if (tid == 0) {
    float s = 0.0f;
    #pragma unroll
    for (int i = 0; i < 8; ++i) s += lred[i];
    lpart[blockIdx.x] = s;
  }
  unsigned int hv = hcnt[tid];
  if (hv) atomicAdd(&counts[tid], hv);
}

// Streaming writer: blocks [0,512) quantized, [512,2560) encodings.
__global__ __launch_bounds__(256) void vq_write(
    const float* __restrict__ W, const unsigned short* __restrict__ idx,
    float* __restrict__ out) {
  int bid = blockIdx.x;
  if (bid < 512) {
    float* quant = out + QUANT_OFF;
    int e = bid * 256 + threadIdx.x;        // stride 131072, 64 iters
    #pragma unroll 4
    for (int i = 0; i < 64; ++i, e += 131072) {
      int b = e >> 18, r = e & 262143;
      int ch = r >> 12, hw = r & 4095;
      int n = (b << 12) | hw;
      float v = W[((int)idx[n] << 6) | ch];
      __builtin_nontemporal_store(v, &quant[e]);
    }
  } else {
    f32x2* encb = (f32x2*)(out + ENC_OFF);  // 8-byte aligned
    long long c = (long long)(bid - 512) * 256 + threadIdx.x;  // stride 524288
    #pragma unroll 4
    for (int i = 0; i < 64; ++i, c += 524288) {
      int row = (int)(c >> 8), col2 = (int)(c & 255);
      int bi = idx[row];
      int base = col2 << 1;
      f32x2 v;
      v.x = (bi == base)     ? 1.0f : 0.0f;
      v.y = (bi == base + 1) ? 1.0f : 0.0f;
      __builtin_nontemporal_store(v, &encb[c]);
    }
  }
}

__global__ void vq_final(const unsigned int* __restrict__ counts,
                         const float* __restrict__ lpart,
                         float* __restrict__ out) {
  __shared__ float red[8], red2[8];
  int k = threadIdx.x;  // 512 threads
  float pr = (float)counts[k] * (1.0f / 131072.0f);
  float s = pr * logf(pr + 1e-10f);
  float l = lpart[k] + lpart[k + 512];
  #pragma unroll
  for (int off = 32; off; off >>= 1) {
    s += __shfl_down(s, off, 64);
    l += __shfl_down(l, off, 64);
  }
  if ((k & 63) == 0) { red[k >> 6] = s; red2[k >> 6] = l; }
  __syncthreads();
  if (k == 0) {
    float H = 0.0f, L = 0.0f;
    #pragma unroll
    for (int i = 0; i < 8; ++i) { H += red[i]; L += red2[i]; }
    out[PERP_OFF] = expf(-H);
    out[0] = 1.25f * L * (1.0f / 8388608.0f);
  }
}

extern "C" void kernel_launch(void* const* d_in, const int* in_sizes, int n_in,
                              void* d_out, int out_size, void* d_ws, size_t ws_size,
                              hipStream_t stream) {
  (void)in_sizes; (void)n_in; (void)out_size; (void)ws_size;
  const float* x = (const float*)d_in[0];
  const float* W = (const float*)d_in[1];
  float* out = (float*)d_out;

  char* ws = (char*)d_ws;
  unsigned int* counts = (unsigned int*)ws;
  float* sw2           = (float*)(ws + 2048);
  float* lpart         = (float*)(ws + 4096);
  unsigned short* w2   = (unsigned short*)(ws + 8192);
  unsigned short* idx  = (unsigned short*)(ws + 73728);

  hipMemsetAsync(ws, 0, 2048, stream);
  vq_prep<<<512, 64, 0, stream>>>(W, sw2, w2);
  vq_argmin<<<1024, 512, 0, stream>>>(x, w2, sw2, idx, counts, lpart);
  vq_write<<<2560, 256, 0, stream>>>(W, idx, out);
  vq_final<<<1, 512, 0, stream>>>(counts, lpart, out);
}

// Round 7
// 122.049 us; speedup vs baseline: 5.6430x; 1.3369x over previous
//
#include <hip/hip_runtime.h>

// Output layout (floats): [0]=loss, [1..8388608]=quantized BCHW,
// [8388609]=perplexity, [8388610..]=encodings (N x K)
#define QUANT_OFF 1
#define PERP_OFF 8388609
#define ENC_OFF  8388610

// ws: [0,2048)    counts u32[512]
//     [2048,4096) sw2 f32[512]
//     [4096,8192) loss partials f32[1024]
//     [8192,73728)   w2 bf16[512*64]  (-2W)
//     [73728,335872) idx u16[131072]

typedef __attribute__((ext_vector_type(8))) short bf16x8;
typedef __attribute__((ext_vector_type(2))) float f32x2;
typedef __attribute__((ext_vector_type(4))) float f32x4;

__device__ __forceinline__ unsigned short f2bf(float f) {
  unsigned int u = __float_as_uint(f);
  u += 0x7fffu + ((u >> 16) & 1u);
  return (unsigned short)(u >> 16);
}

__global__ void vq_prep(const float* __restrict__ W, float* __restrict__ sw2,
                        unsigned short* __restrict__ w2) {
  int k = blockIdx.x;     // 512 blocks
  int d = threadIdx.x;    // 64 threads
  float wd = W[k * 64 + d];
  w2[k * 64 + d] = f2bf(-2.0f * wd);
  float s = wd * wd;
  #pragma unroll
  for (int off = 32; off; off >>= 1) s += __shfl_down(s, off, 64);
  if (d == 0) sw2[k] = s;
}

// 512 thr = 8 waves; wave owns 16 points; block = 128 points; grid = 1024.
// score[k] = sw2[k] + x . (-2 W[k]) via mfma_16x16x32_bf16 with C-init = sw2.
// LDS W layout: row stride 72 ushorts (144B) -> bank-quad (row+chunk)%8,
// conflict-free beyond the BW floor (old XOR swizzle aliased all rows).
__global__ __launch_bounds__(512) void vq_argmin(
    const float* __restrict__ x, const unsigned short* __restrict__ w2,
    const float* __restrict__ sw2g, unsigned short* __restrict__ idx,
    unsigned int* __restrict__ counts, float* __restrict__ lpart) {
  __shared__ unsigned short wlds[512 * 72];  // 73728 B, padded rows
  __shared__ float sw2s[512];
  __shared__ unsigned int hcnt[512];
  __shared__ float lred[8];

  int tid  = threadIdx.x;
  int lane = tid & 63;
  int wv   = tid >> 6;
  int rl   = lane & 15;        // point-in-wave / code-row-in-tile
  int g    = lane >> 4;        // k-group (8 dims) / acc row-group
  int n0   = (blockIdx.x << 7) + (wv << 4);   // wave's first point
  int b    = n0 >> 12;         // 128-pt blocks never cross a batch
  int hw0  = n0 & 4095;
  const float* xb = x + b * 262144 + hw0 + rl;   // channel stride 4096

  hcnt[tid] = 0u;
  sw2s[tid] = sw2g[tid];

  // x: 16 dims per lane (dims g*8+e+32s of point rl)
  float xr[16];
  #pragma unroll
  for (int s = 0; s < 2; ++s)
    #pragma unroll
    for (int e = 0; e < 8; ++e)
      xr[s * 8 + e] = xb[(g * 8 + e + 32 * s) * 4096];

  // stage pre-packed bf16 (-2W) into padded LDS (unit = 16B = 8 bf16)
  #pragma unroll
  for (int i = 0; i < 8; ++i) {
    int u = (i << 9) + tid;          // 4096 units
    int r = u >> 3, c = u & 7;
    bf16x8 v = *(const bf16x8*)&w2[u * 8];
    *(bf16x8*)&wlds[r * 72 + c * 8] = v;
  }

  // B-frags + ||x||^2
  float cnp = 0.0f;
  bf16x8 xf0, xf1;
  #pragma unroll
  for (int e = 0; e < 8; ++e) {
    xf0[e] = f2bf(xr[e]);     cnp = fmaf(xr[e], xr[e], cnp);
    xf1[e] = f2bf(xr[8 + e]); cnp = fmaf(xr[8 + e], xr[8 + e], cnp);
  }
  float cn = cnp + __shfl_xor(cnp, 16);
  cn += __shfl_xor(cn, 32);

  __syncthreads();

  // 32 code-tiles: 2 MFMA each; idx packed into low 9 mantissa bits
  float best = __uint_as_float(0x7f7fffffu);
  int rowoff = rl * 72 + g * 8;
  #pragma unroll
  for (int t = 0; t < 32; ++t) {
    f32x4 acc = *(const f32x4*)&sw2s[t * 16 + g * 4];
    int tb = t * 1152 + rowoff;
    bf16x8 a0 = *(const bf16x8*)&wlds[tb];        // dims [g*8, g*8+8)
    bf16x8 a1 = *(const bf16x8*)&wlds[tb + 32];   // dims [32+g*8, ...)
    acc = __builtin_amdgcn_mfma_f32_16x16x32_bf16(a0, xf0, acc, 0, 0, 0);
    acc = __builtin_amdgcn_mfma_f32_16x16x32_bf16(a1, xf1, acc, 0, 0, 0);
    #pragma unroll
    for (int j = 0; j < 4; ++j) {
      unsigned int pk = (__float_as_uint(acc[j]) & ~511u) | (t * 16 + g * 4 + j);
      best = fminf(best, __uint_as_float(pk));
    }
  }
  best = fminf(best, __shfl_xor(best, 16));
  best = fminf(best, __shfl_xor(best, 32));
  int bi = __float_as_uint(best) & 511;
  float score = __uint_as_float(__float_as_uint(best) & ~511u);

  if (lane < 16) {
    idx[n0 + lane] = (unsigned short)bi;
    atomicAdd(&hcnt[bi], 1u);
  }

  // loss: 4 copies per point across the wave -> sum * 0.25
  float dl = cn + score;
  #pragma unroll
  for (int off = 1; off < 64; off <<= 1) dl += __shfl_xor(dl, off);
  if (lane == 0) lred[wv] = dl * 0.25f;

  __syncthreads();
  if (tid == 0) {
    float s = 0.0f;
    #pragma unroll
    for (int i = 0; i < 8; ++i) s += lred[i];
    lpart[blockIdx.x] = s;
  }
  unsigned int hv = hcnt[tid];
  if (hv) atomicAdd(&counts[tid], hv);
}

// Streaming writer, PLAIN stores (the 6.9 TB/s fill-kernel regime).
// Blocks [0,512): quantized dwords. Blocks [512,2560): enc one-hot f32x2,
// row index SGPR-uniform -> s_load idx + broadcast compare.
__global__ __launch_bounds__(256) void vq_write(
    const float* __restrict__ W, const unsigned short* __restrict__ idx,
    float* __restrict__ out) {
  int bid = blockIdx.x;
  int tid = threadIdx.x;
  if (bid < 512) {
    float* quant = out + QUANT_OFF;
    int e = bid * 256 + tid;        // stride 131072, 64 iters
    #pragma unroll 4
    for (int i = 0; i < 64; ++i, e += 131072) {
      int b = e >> 18, r = e & 262143;
      int ch = r >> 12, hw = r & 4095;
      int n = (b << 12) | hw;
      quant[e] = W[((int)idx[n] << 6) | ch];
    }
  } else {
    f32x2* encb = (f32x2*)(out + ENC_OFF);  // 8-byte aligned
    int rb = bid - 512;                     // 2048 enc blocks
    int c0 = tid << 1;
    #pragma unroll 4
    for (int i = 0; i < 64; ++i) {
      int row = rb + (i << 11);             // no tid term -> SGPR
      int bi = idx[row];
      f32x2 v;
      v.x = (bi == c0)     ? 1.0f : 0.0f;
      v.y = (bi == c0 + 1) ? 1.0f : 0.0f;
      encb[((long long)row << 8) + tid] = v;
    }
  }
}

__global__ void vq_final(const unsigned int* __restrict__ counts,
                         const float* __restrict__ lpart,
                         float* __restrict__ out) {
  __shared__ float red[8], red2[8];
  int k = threadIdx.x;  // 512 threads
  float pr = (float)counts[k] * (1.0f / 131072.0f);
  float s = pr * logf(pr + 1e-10f);
  float l = lpart[k] + lpart[k + 512];
  #pragma unroll
  for (int off = 32; off; off >>= 1) {
    s += __shfl_down(s, off, 64);
    l += __shfl_down(l, off, 64);
  }
  if ((k & 63) == 0) { red[k >> 6] = s; red2[k >> 6] = l; }
  __syncthreads();
  if (k == 0) {
    float H = 0.0f, L = 0.0f;
    #pragma unroll
    for (int i = 0; i < 8; ++i) { H += red[i]; L += red2[i]; }
    out[PERP_OFF] = expf(-H);
    out[0] = 1.25f * L * (1.0f / 8388608.0f);
  }
}

extern "C" void kernel_launch(void* const* d_in, const int* in_sizes, int n_in,
                              void* d_out, int out_size, void* d_ws, size_t ws_size,
                              hipStream_t stream) {
  (void)in_sizes; (void)n_in; (void)out_size; (void)ws_size;
  const float* x = (const float*)d_in[0];
  const float* W = (const float*)d_in[1];
  float* out = (float*)d_out;

  char* ws = (char*)d_ws;
  unsigned int* counts = (unsigned int*)ws;
  float* sw2           = (float*)(ws + 2048);
  float* lpart         = (float*)(ws + 4096);
  unsigned short* w2   = (unsigned short*)(ws + 8192);
  unsigned short* idx  = (unsigned short*)(ws + 73728);

  hipMemsetAsync(ws, 0, 2048, stream);
  vq_prep<<<512, 64, 0, stream>>>(W, sw2, w2);
  vq_argmin<<<1024, 512, 0, stream>>>(x, w2, sw2, idx, counts, lpart);
  vq_write<<<2560, 256, 0, stream>>>(W, idx, out);
  vq_final<<<1, 512, 0, stream>>>(counts, lpart, out);
}

// Round 8
// 118.669 us; speedup vs baseline: 5.8037x; 1.0285x over previous
//
#include <hip/hip_runtime.h>

// Output layout (floats): [0]=loss, [1..8388608]=quantized BCHW,
// [8388609]=perplexity, [8388610..]=encodings (N x K)
#define QUANT_OFF 1
#define PERP_OFF 8388609
#define ENC_OFF  8388610

// ws: [0,2048)    counts u32[512]
//     [2048,4096) sw2 f32[512]
//     [4096,8192) loss partials f32[1024]
//     [8192,73728)   w2 bf16[512*64]  (-2W)
//     [73728,335872) idx u16[131072]

typedef __attribute__((ext_vector_type(8))) short bf16x8;
typedef __attribute__((ext_vector_type(2))) float f32x2;
typedef __attribute__((ext_vector_type(4))) float f32x4;

__device__ __forceinline__ unsigned short f2bf(float f) {
  unsigned int u = __float_as_uint(f);
  u += 0x7fffu + ((u >> 16) & 1u);
  return (unsigned short)(u >> 16);
}

__global__ void vq_prep(const float* __restrict__ W, float* __restrict__ sw2,
                        unsigned short* __restrict__ w2) {
  int k = blockIdx.x;     // 512 blocks
  int d = threadIdx.x;    // 64 threads
  float wd = W[k * 64 + d];
  w2[k * 64 + d] = f2bf(-2.0f * wd);
  float s = wd * wd;
  #pragma unroll
  for (int off = 32; off; off >>= 1) s += __shfl_down(s, off, 64);
  if (d == 0) sw2[k] = s;
}

// 512 thr = 8 waves; wave owns 32 points (two 16-pt column sets sharing each
// A-frag read); block = 256 points; grid = 512 -> one 2-block round per CU.
// score[k] = sw2[k] + x.(-2W[k]) via mfma_16x16x32_bf16, C-init = sw2.
// LDS rows padded to 144B -> 2-way banks (free) on A-frag reads.
__global__ __launch_bounds__(512, 4) void vq_argmin(
    const float* __restrict__ x, const unsigned short* __restrict__ w2,
    const float* __restrict__ sw2g, unsigned short* __restrict__ idx,
    unsigned int* __restrict__ counts, float* __restrict__ lpart) {
  __shared__ unsigned short wlds[512 * 72];  // 73728 B, padded rows
  __shared__ float sw2s[512];
  __shared__ unsigned int hcnt[512];
  __shared__ float lred[8];

  int tid  = threadIdx.x;
  int lane = tid & 63;
  int wv   = tid >> 6;
  int rl   = lane & 15;        // column (point-in-set) / code-row-in-tile
  int g    = lane >> 4;        // k-group (8 dims) / acc row-group
  int n0   = (blockIdx.x << 8) + (wv << 5);   // wave's first point (32/wave)
  int b    = n0 >> 12;         // 256-pt blocks never cross a batch
  int hw0  = n0 & 4095;
  const float* xb = x + b * 262144 + hw0;     // channel stride 4096

  hcnt[tid] = 0u;
  sw2s[tid] = sw2g[tid];

  // x load + bf16 convert, two point sets (rl and rl+16); no xr[] array
  bf16x8 xfA0, xfA1, xfB0, xfB1;
  float cnA = 0.0f, cnB = 0.0f;
  #pragma unroll
  for (int e = 0; e < 8; ++e) {
    int d0 = (g * 8 + e) * 4096, d1 = (32 + g * 8 + e) * 4096;
    float a0 = xb[d0 + rl],      a1 = xb[d1 + rl];
    float b0 = xb[d0 + 16 + rl], b1 = xb[d1 + 16 + rl];
    cnA = fmaf(a0, a0, fmaf(a1, a1, cnA));
    cnB = fmaf(b0, b0, fmaf(b1, b1, cnB));
    xfA0[e] = f2bf(a0); xfA1[e] = f2bf(a1);
    xfB0[e] = f2bf(b0); xfB1[e] = f2bf(b1);
  }
  cnA += __shfl_xor(cnA, 16); cnA += __shfl_xor(cnA, 32);
  cnB += __shfl_xor(cnB, 16); cnB += __shfl_xor(cnB, 32);

  // stage pre-packed bf16 (-2W) into padded LDS (unit = 16B = 8 bf16)
  #pragma unroll
  for (int i = 0; i < 8; ++i) {
    int u = (i << 9) + tid;          // 4096 units
    int r = u >> 3, c = u & 7;
    bf16x8 v = *(const bf16x8*)&w2[u * 8];
    *(bf16x8*)&wlds[r * 72 + c * 8] = v;
  }
  __syncthreads();

  // 32 code-tiles: shared A-frags feed BOTH point sets (4 MFMA/tile)
  float bestA = __uint_as_float(0x7f7fffffu);
  float bestB = __uint_as_float(0x7f7fffffu);
  int rowoff = rl * 72 + g * 8;
  #pragma unroll
  for (int t = 0; t < 32; ++t) {
    f32x4 sv = *(const f32x4*)&sw2s[t * 16 + g * 4];
    int tb = t * 1152 + rowoff;
    bf16x8 a0 = *(const bf16x8*)&wlds[tb];        // dims [g*8, g*8+8)
    bf16x8 a1 = *(const bf16x8*)&wlds[tb + 32];   // dims [32+g*8, ...)
    f32x4 accA = sv, accB = sv;
    accA = __builtin_amdgcn_mfma_f32_16x16x32_bf16(a0, xfA0, accA, 0, 0, 0);
    accA = __builtin_amdgcn_mfma_f32_16x16x32_bf16(a1, xfA1, accA, 0, 0, 0);
    accB = __builtin_amdgcn_mfma_f32_16x16x32_bf16(a0, xfB0, accB, 0, 0, 0);
    accB = __builtin_amdgcn_mfma_f32_16x16x32_bf16(a1, xfB1, accB, 0, 0, 0);
    #pragma unroll
    for (int j = 0; j < 4; ++j) {
      unsigned int ki = (unsigned int)(t * 16 + g * 4 + j);
      unsigned int pA = (__float_as_uint(accA[j]) & ~511u) | ki;
      unsigned int pB = (__float_as_uint(accB[j]) & ~511u) | ki;
      bestA = fminf(bestA, __uint_as_float(pA));
      bestB = fminf(bestB, __uint_as_float(pB));
    }
  }
  bestA = fminf(bestA, __shfl_xor(bestA, 16));
  bestA = fminf(bestA, __shfl_xor(bestA, 32));
  bestB = fminf(bestB, __shfl_xor(bestB, 16));
  bestB = fminf(bestB, __shfl_xor(bestB, 32));
  int biA = __float_as_uint(bestA) & 511;
  int biB = __float_as_uint(bestB) & 511;
  float scoreA = __uint_as_float(__float_as_uint(bestA) & ~511u);
  float scoreB = __uint_as_float(__float_as_uint(bestB) & ~511u);

  if (lane < 16) {
    idx[n0 + rl] = (unsigned short)biA;
    atomicAdd(&hcnt[biA], 1u);
  } else if (lane < 32) {
    idx[n0 + 16 + rl] = (unsigned short)biB;
    atomicAdd(&hcnt[biB], 1u);
  }

  // loss: each point appears 4x across the wave -> sum * 0.25
  float dl = (cnA + scoreA) + (cnB + scoreB);
  #pragma unroll
  for (int off = 1; off < 64; off <<= 1) dl += __shfl_xor(dl, off);
  if (lane == 0) lred[wv] = dl * 0.25f;

  __syncthreads();
  if (tid == 0) {
    float s = 0.0f;
    #pragma unroll
    for (int i = 0; i < 8; ++i) s += lred[i];
    lpart[blockIdx.x] = s;
  }
  unsigned int hv = hcnt[tid];
  if (hv) atomicAdd(&counts[tid], hv);
}

// Streaming writer, PLAIN stores (the 6.9 TB/s fill-kernel regime).
// Blocks [0,512): quantized dwords. Blocks [512,2560): enc one-hot f32x2,
// row index SGPR-uniform -> s_load idx + broadcast compare.
__global__ __launch_bounds__(256) void vq_write(
    const float* __restrict__ W, const unsigned short* __restrict__ idx,
    float* __restrict__ out) {
  int bid = blockIdx.x;
  int tid = threadIdx.x;
  if (bid < 512) {
    float* quant = out + QUANT_OFF;
    int e = bid * 256 + tid;        // stride 131072, 64 iters
    #pragma unroll 4
    for (int i = 0; i < 64; ++i, e += 131072) {
      int b = e >> 18, r = e & 262143;
      int ch = r >> 12, hw = r & 4095;
      int n = (b << 12) | hw;
      quant[e] = W[((int)idx[n] << 6) | ch];
    }
  } else {
    f32x2* encb = (f32x2*)(out + ENC_OFF);  // 8-byte aligned
    int rb = bid - 512;                     // 2048 enc blocks
    int c0 = tid << 1;
    #pragma unroll 4
    for (int i = 0; i < 64; ++i) {
      int row = rb + (i << 11);             // no tid term -> SGPR
      int bi = idx[row];
      f32x2 v;
      v.x = (bi == c0)     ? 1.0f : 0.0f;
      v.y = (bi == c0 + 1) ? 1.0f : 0.0f;
      encb[((long long)row << 8) + tid] = v;
    }
  }
}

__global__ void vq_final(const unsigned int* __restrict__ counts,
                         const float* __restrict__ lpart,
                         float* __restrict__ out) {
  __shared__ float red[8], red2[8];
  int k = threadIdx.x;  // 512 threads
  float pr = (float)counts[k] * (1.0f / 131072.0f);
  float s = pr * logf(pr + 1e-10f);
  float l = lpart[k];
  #pragma unroll
  for (int off = 32; off; off >>= 1) {
    s += __shfl_down(s, off, 64);
    l += __shfl_down(l, off, 64);
  }
  if ((k & 63) == 0) { red[k >> 6] = s; red2[k >> 6] = l; }
  __syncthreads();
  if (k == 0) {
    float H = 0.0f, L = 0.0f;
    #pragma unroll
    for (int i = 0; i < 8; ++i) { H += red[i]; L += red2[i]; }
    out[PERP_OFF] = expf(-H);
    out[0] = 1.25f * L * (1.0f / 8388608.0f);
  }
}

extern "C" void kernel_launch(void* const* d_in, const int* in_sizes, int n_in,
                              void* d_out, int out_size, void* d_ws, size_t ws_size,
                              hipStream_t stream) {
  (void)in_sizes; (void)n_in; (void)out_size; (void)ws_size;
  const float* x = (const float*)d_in[0];
  const float* W = (const float*)d_in[1];
  float* out = (float*)d_out;

  char* ws = (char*)d_ws;
  unsigned int* counts = (unsigned int*)ws;
  float* sw2           = (float*)(ws + 2048);
  float* lpart         = (float*)(ws + 4096);
  unsigned short* w2   = (unsigned short*)(ws + 8192);
  unsigned short* idx  = (unsigned short*)(ws + 73728);

  hipMemsetAsync(ws, 0, 4096, stream);   // counts + (unused tail) zeroed; lpart written fully
  vq_prep<<<512, 64, 0, stream>>>(W, sw2, w2);
  vq_argmin<<<512, 512, 0, stream>>>(x, w2, sw2, idx, counts, lpart);
  vq_write<<<2560, 256, 0, stream>>>(W, idx, out);
  vq_final<<<1, 512, 0, stream>>>(counts, lpart, out);
}

// Round 9
// 94.704 us; speedup vs baseline: 7.2723x; 1.2530x over previous
//
#include <hip/hip_runtime.h>

// Output layout (floats): [0]=loss, [1..8388608]=quantized BCHW,
// [8388609]=perplexity, [8388610..]=encodings (N x K)
#define QUANT_OFF 1
#define PERP_OFF 8388609
#define ENC_OFF  8388610

// ws: [0,2048)    counts u32[512]
//     [2048,4096) sw2 f32[512]
//     [4096,8192) loss partials f32[1024]
//     [8192,73728)   w2 bf16[512*64]  (-2W)
//     [73728,598016) idx u32[131072]

typedef __attribute__((ext_vector_type(8))) short bf16x8;
typedef __attribute__((ext_vector_type(2))) float f32x2;
typedef __attribute__((ext_vector_type(4))) float f32x4;

__device__ __forceinline__ unsigned short f2bf(float f) {
  unsigned int u = __float_as_uint(f);
  u += 0x7fffu + ((u >> 16) & 1u);
  return (unsigned short)(u >> 16);
}

// 512 blocks x 64 thr: sw2, bf16(-2W) pack, and counts zeroing (kills memset)
__global__ void vq_prep(const float* __restrict__ W, float* __restrict__ sw2,
                        unsigned short* __restrict__ w2,
                        unsigned int* __restrict__ counts) {
  int k = blockIdx.x;
  int d = threadIdx.x;
  float wd = W[k * 64 + d];
  w2[k * 64 + d] = f2bf(-2.0f * wd);
  float s = wd * wd;
  #pragma unroll
  for (int off = 32; off; off >>= 1) s += __shfl_down(s, off, 64);
  if (d == 0) { sw2[k] = s; counts[k] = 0u; }
}

// 512 thr = 8 waves; wave owns 32 points (two 16-pt column sets sharing each
// A-frag read); block = 256 points; grid = 512 -> one 2-block round per CU.
// score[k] = sw2[k] + x.(-2W[k]) via mfma_16x16x32_bf16, C-init = sw2.
// LDS rows padded to 144B -> 2-way banks (free) on A-frag reads.
__global__ __launch_bounds__(512, 4) void vq_argmin(
    const float* __restrict__ x, const unsigned short* __restrict__ w2,
    const float* __restrict__ sw2g, unsigned int* __restrict__ idx,
    unsigned int* __restrict__ counts, float* __restrict__ lpart) {
  __shared__ unsigned short wlds[512 * 72];  // 73728 B, padded rows
  __shared__ float sw2s[512];
  __shared__ unsigned int hcnt[512];
  __shared__ float lred[8];

  int tid  = threadIdx.x;
  int lane = tid & 63;
  int wv   = tid >> 6;
  int rl   = lane & 15;        // column (point-in-set) / code-row-in-tile
  int g    = lane >> 4;        // k-group (8 dims) / acc row-group
  int n0   = (blockIdx.x << 8) + (wv << 5);   // wave's first point (32/wave)
  int b    = n0 >> 12;         // 256-pt blocks never cross a batch
  int hw0  = n0 & 4095;
  const float* xb = x + b * 262144 + hw0;     // channel stride 4096

  hcnt[tid] = 0u;
  sw2s[tid] = sw2g[tid];

  // x load + bf16 convert, two point sets (rl and rl+16)
  bf16x8 xfA0, xfA1, xfB0, xfB1;
  float cnA = 0.0f, cnB = 0.0f;
  #pragma unroll
  for (int e = 0; e < 8; ++e) {
    int d0 = (g * 8 + e) * 4096, d1 = (32 + g * 8 + e) * 4096;
    float a0 = xb[d0 + rl],      a1 = xb[d1 + rl];
    float b0 = xb[d0 + 16 + rl], b1 = xb[d1 + 16 + rl];
    cnA = fmaf(a0, a0, fmaf(a1, a1, cnA));
    cnB = fmaf(b0, b0, fmaf(b1, b1, cnB));
    xfA0[e] = f2bf(a0); xfA1[e] = f2bf(a1);
    xfB0[e] = f2bf(b0); xfB1[e] = f2bf(b1);
  }
  cnA += __shfl_xor(cnA, 16); cnA += __shfl_xor(cnA, 32);
  cnB += __shfl_xor(cnB, 16); cnB += __shfl_xor(cnB, 32);

  // stage pre-packed bf16 (-2W) into padded LDS (unit = 16B = 8 bf16)
  #pragma unroll
  for (int i = 0; i < 8; ++i) {
    int u = (i << 9) + tid;          // 4096 units
    int r = u >> 3, c = u & 7;
    bf16x8 v = *(const bf16x8*)&w2[u * 8];
    *(bf16x8*)&wlds[r * 72 + c * 8] = v;
  }
  __syncthreads();

  // 32 code-tiles: shared A-frags feed BOTH point sets (4 MFMA/tile)
  float bestA = __uint_as_float(0x7f7fffffu);
  float bestB = __uint_as_float(0x7f7fffffu);
  int rowoff = rl * 72 + g * 8;
  #pragma unroll
  for (int t = 0; t < 32; ++t) {
    f32x4 sv = *(const f32x4*)&sw2s[t * 16 + g * 4];
    int tb = t * 1152 + rowoff;
    bf16x8 a0 = *(const bf16x8*)&wlds[tb];        // dims [g*8, g*8+8)
    bf16x8 a1 = *(const bf16x8*)&wlds[tb + 32];   // dims [32+g*8, ...)
    f32x4 accA = sv, accB = sv;
    accA = __builtin_amdgcn_mfma_f32_16x16x32_bf16(a0, xfA0, accA, 0, 0, 0);
    accA = __builtin_amdgcn_mfma_f32_16x16x32_bf16(a1, xfA1, accA, 0, 0, 0);
    accB = __builtin_amdgcn_mfma_f32_16x16x32_bf16(a0, xfB0, accB, 0, 0, 0);
    accB = __builtin_amdgcn_mfma_f32_16x16x32_bf16(a1, xfB1, accB, 0, 0, 0);
    #pragma unroll
    for (int j = 0; j < 4; ++j) {
      unsigned int ki = (unsigned int)(t * 16 + g * 4 + j);
      unsigned int pA = (__float_as_uint(accA[j]) & ~511u) | ki;
      unsigned int pB = (__float_as_uint(accB[j]) & ~511u) | ki;
      bestA = fminf(bestA, __uint_as_float(pA));
      bestB = fminf(bestB, __uint_as_float(pB));
    }
  }
  bestA = fminf(bestA, __shfl_xor(bestA, 16));
  bestA = fminf(bestA, __shfl_xor(bestA, 32));
  bestB = fminf(bestB, __shfl_xor(bestB, 16));
  bestB = fminf(bestB, __shfl_xor(bestB, 32));
  int biA = __float_as_uint(bestA) & 511;
  int biB = __float_as_uint(bestB) & 511;
  float scoreA = __uint_as_float(__float_as_uint(bestA) & ~511u);
  float scoreB = __uint_as_float(__float_as_uint(bestB) & ~511u);

  if (lane < 16) {
    idx[n0 + rl] = (unsigned int)biA;
    atomicAdd(&hcnt[biA], 1u);
  } else if (lane < 32) {
    idx[n0 + 16 + rl] = (unsigned int)biB;
    atomicAdd(&hcnt[biB], 1u);
  }

  // loss: each point appears 4x across the wave -> sum * 0.25
  float dl = (cnA + scoreA) + (cnB + scoreB);
  #pragma unroll
  for (int off = 1; off < 64; off <<= 1) dl += __shfl_xor(dl, off);
  if (lane == 0) lred[wv] = dl * 0.25f;

  __syncthreads();
  if (tid == 0) {
    float s = 0.0f;
    #pragma unroll
    for (int i = 0; i < 8; ++i) s += lred[i];
    lpart[blockIdx.x] = s;
  }
  unsigned int hv = hcnt[tid];
  if (hv) atomicAdd(&counts[tid], hv);
}

// Streaming writer + fused finalizer. Plain stores, CONTIGUOUS per block:
//  blocks [0,512):    quantized, 64KB linear stream each
//  blocks [512,2560): encodings, 128KB linear stream each (rows rb*64..+64),
//                     per-row code id is a wave-uniform s_load
//  block 2560:        loss + perplexity (counts/lpart complete at launch)
__global__ __launch_bounds__(256) void vq_write(
    const float* __restrict__ W, const unsigned int* __restrict__ idx,
    const unsigned int* __restrict__ counts, const float* __restrict__ lpart,
    float* __restrict__ out) {
  int bid = blockIdx.x;
  int tid = threadIdx.x;
  if (bid < 512) {
    float* quant = out + QUANT_OFF;
    int e0 = bid << 14;                    // 16384 elems per block
    #pragma unroll 4
    for (int i = 0; i < 64; ++i) {
      int e = e0 + (i << 8) + tid;
      int b = e >> 18, ch = (e >> 12) & 63, hw = e & 4095;
      int n = (b << 12) | hw;
      quant[e] = W[(idx[n] << 6) | ch];
    }
  } else if (bid < 2560) {
    f32x2* encb = (f32x2*)(out + ENC_OFF);  // 8-byte aligned
    int row0 = (bid - 512) << 6;            // 64 consecutive rows
    int c0 = tid << 1;
    #pragma unroll 8
    for (int i = 0; i < 64; ++i) {
      int row = row0 + i;
      int bi = (int)idx[row];               // uniform -> s_load + broadcast
      f32x2 v;
      v.x = (bi == c0)     ? 1.0f : 0.0f;
      v.y = (bi == c0 + 1) ? 1.0f : 0.0f;
      encb[(row << 8) + tid] = v;
    }
  } else {
    // finalizer: 256 threads cover 512 codes / 512 loss partials
    __shared__ float red[4], red2[4];
    float pr0 = (float)counts[tid]       * (1.0f / 131072.0f);
    float pr1 = (float)counts[tid + 256] * (1.0f / 131072.0f);
    float s = pr0 * logf(pr0 + 1e-10f) + pr1 * logf(pr1 + 1e-10f);
    float l = lpart[tid] + lpart[tid + 256];
    #pragma unroll
    for (int off = 32; off; off >>= 1) {
      s += __shfl_down(s, off, 64);
      l += __shfl_down(l, off, 64);
    }
    if ((tid & 63) == 0) { red[tid >> 6] = s; red2[tid >> 6] = l; }
    __syncthreads();
    if (tid == 0) {
      float H = 0.0f, L = 0.0f;
      #pragma unroll
      for (int i = 0; i < 4; ++i) { H += red[i]; L += red2[i]; }
      out[PERP_OFF] = expf(-H);
      out[0] = 1.25f * L * (1.0f / 8388608.0f);
    }
  }
}

extern "C" void kernel_launch(void* const* d_in, const int* in_sizes, int n_in,
                              void* d_out, int out_size, void* d_ws, size_t ws_size,
                              hipStream_t stream) {
  (void)in_sizes; (void)n_in; (void)out_size; (void)ws_size;
  const float* x = (const float*)d_in[0];
  const float* W = (const float*)d_in[1];
  float* out = (float*)d_out;

  char* ws = (char*)d_ws;
  unsigned int* counts = (unsigned int*)ws;
  float* sw2           = (float*)(ws + 2048);
  float* lpart         = (float*)(ws + 4096);
  unsigned short* w2   = (unsigned short*)(ws + 8192);
  unsigned int* idx    = (unsigned int*)(ws + 73728);

  vq_prep<<<512, 64, 0, stream>>>(W, sw2, w2, counts);
  vq_argmin<<<512, 512, 0, stream>>>(x, w2, sw2, idx, counts, lpart);
  vq_write<<<2561, 256, 0, stream>>>(W, idx, counts, lpart, out);
}

// Round 10
// 91.892 us; speedup vs baseline: 7.4949x; 1.0306x over previous
//
#include <hip/hip_runtime.h>

// Output layout (floats): [0]=loss, [1..8388608]=quantized BCHW,
// [8388609]=perplexity, [8388610..]=encodings (N x K)
#define QUANT_OFF 1
#define PERP_OFF 8388609
#define ENC_OFF  8388610

// ws: [0,2048)    counts u32[512]
//     [2048,4096) sw2 f32[512]
//     [4096,8192) loss partials f32[1024]
//     [8192,73728)   w2 bf16[512*64]  (-2W)
//     [73728,598016) idx u32[131072]

typedef __attribute__((ext_vector_type(8))) short bf16x8;
typedef __attribute__((ext_vector_type(2))) float f32x2;
typedef __attribute__((ext_vector_type(4))) float f32x4;

__device__ __forceinline__ unsigned short f2bf(float f) {
  unsigned int u = __float_as_uint(f);
  u += 0x7fffu + ((u >> 16) & 1u);
  return (unsigned short)(u >> 16);
}

// 512 blocks x 64 thr: sw2, bf16(-2W) pack, counts zeroing
__global__ void vq_prep(const float* __restrict__ W, float* __restrict__ sw2,
                        unsigned short* __restrict__ w2,
                        unsigned int* __restrict__ counts) {
  int k = blockIdx.x;
  int d = threadIdx.x;
  float wd = W[k * 64 + d];
  w2[k * 64 + d] = f2bf(-2.0f * wd);
  float s = wd * wd;
  #pragma unroll
  for (int off = 32; off; off >>= 1) s += __shfl_down(s, off, 64);
  if (d == 0) { sw2[k] = s; counts[k] = 0u; }
}

// 512 thr = 8 waves; wave owns 32 points; block = 256 points; grid = 512.
// score[k] = sw2[k] + x.(-2W[k]) via mfma_16x16x32_bf16, C-init = sw2.
// NEW: each wave streams its 32 one-hot enc rows (64KB contiguous) in the
// tail -> the 268MB enc write overlaps other blocks' compute phases.
__global__ __launch_bounds__(512, 4) void vq_argmin(
    const float* __restrict__ x, const unsigned short* __restrict__ w2,
    const float* __restrict__ sw2g, unsigned int* __restrict__ idx,
    unsigned int* __restrict__ counts, float* __restrict__ lpart,
    float* __restrict__ out) {
  __shared__ unsigned short wlds[512 * 72];  // 73728 B, padded rows
  __shared__ float sw2s[512];
  __shared__ unsigned int hcnt[512];
  __shared__ float lred[8];

  int tid  = threadIdx.x;
  int lane = tid & 63;
  int wv   = tid >> 6;
  int rl   = lane & 15;        // column (point-in-set) / code-row-in-tile
  int g    = lane >> 4;        // k-group (8 dims) / acc row-group
  int n0   = (blockIdx.x << 8) + (wv << 5);   // wave's first point (32/wave)
  int b    = n0 >> 12;         // 256-pt blocks never cross a batch
  int hw0  = n0 & 4095;
  const float* xb = x + b * 262144 + hw0;     // channel stride 4096

  hcnt[tid] = 0u;
  sw2s[tid] = sw2g[tid];

  // x load + bf16 convert, two point sets (rl and rl+16)
  bf16x8 xfA0, xfA1, xfB0, xfB1;
  float cnA = 0.0f, cnB = 0.0f;
  #pragma unroll
  for (int e = 0; e < 8; ++e) {
    int d0 = (g * 8 + e) * 4096, d1 = (32 + g * 8 + e) * 4096;
    float a0 = xb[d0 + rl],      a1 = xb[d1 + rl];
    float b0 = xb[d0 + 16 + rl], b1 = xb[d1 + 16 + rl];
    cnA = fmaf(a0, a0, fmaf(a1, a1, cnA));
    cnB = fmaf(b0, b0, fmaf(b1, b1, cnB));
    xfA0[e] = f2bf(a0); xfA1[e] = f2bf(a1);
    xfB0[e] = f2bf(b0); xfB1[e] = f2bf(b1);
  }
  cnA += __shfl_xor(cnA, 16); cnA += __shfl_xor(cnA, 32);
  cnB += __shfl_xor(cnB, 16); cnB += __shfl_xor(cnB, 32);

  // stage pre-packed bf16 (-2W) into padded LDS (unit = 16B = 8 bf16)
  #pragma unroll
  for (int i = 0; i < 8; ++i) {
    int u = (i << 9) + tid;          // 4096 units
    int r = u >> 3, c = u & 7;
    bf16x8 v = *(const bf16x8*)&w2[u * 8];
    *(bf16x8*)&wlds[r * 72 + c * 8] = v;
  }
  __syncthreads();

  // 32 code-tiles: shared A-frags feed BOTH point sets (4 MFMA/tile)
  float bestA = __uint_as_float(0x7f7fffffu);
  float bestB = __uint_as_float(0x7f7fffffu);
  int rowoff = rl * 72 + g * 8;
  #pragma unroll
  for (int t = 0; t < 32; ++t) {
    f32x4 sv = *(const f32x4*)&sw2s[t * 16 + g * 4];
    int tb = t * 1152 + rowoff;
    bf16x8 a0 = *(const bf16x8*)&wlds[tb];        // dims [g*8, g*8+8)
    bf16x8 a1 = *(const bf16x8*)&wlds[tb + 32];   // dims [32+g*8, ...)
    f32x4 accA = sv, accB = sv;
    accA = __builtin_amdgcn_mfma_f32_16x16x32_bf16(a0, xfA0, accA, 0, 0, 0);
    accA = __builtin_amdgcn_mfma_f32_16x16x32_bf16(a1, xfA1, accA, 0, 0, 0);
    accB = __builtin_amdgcn_mfma_f32_16x16x32_bf16(a0, xfB0, accB, 0, 0, 0);
    accB = __builtin_amdgcn_mfma_f32_16x16x32_bf16(a1, xfB1, accB, 0, 0, 0);
    #pragma unroll
    for (int j = 0; j < 4; ++j) {
      unsigned int ki = (unsigned int)(t * 16 + g * 4 + j);
      unsigned int pA = (__float_as_uint(accA[j]) & ~511u) | ki;
      unsigned int pB = (__float_as_uint(accB[j]) & ~511u) | ki;
      bestA = fminf(bestA, __uint_as_float(pA));
      bestB = fminf(bestB, __uint_as_float(pB));
    }
  }
  bestA = fminf(bestA, __shfl_xor(bestA, 16));
  bestA = fminf(bestA, __shfl_xor(bestA, 32));
  bestB = fminf(bestB, __shfl_xor(bestB, 16));
  bestB = fminf(bestB, __shfl_xor(bestB, 32));
  int biA = __float_as_uint(bestA) & 511;   // lane's result for point rl
  int biB = __float_as_uint(bestB) & 511;   // lane's result for point rl+16
  float scoreA = __uint_as_float(__float_as_uint(bestA) & ~511u);
  float scoreB = __uint_as_float(__float_as_uint(bestB) & ~511u);

  // ---- enc one-hot: wave streams rows [n0, n0+32) = 64KB contiguous.
  // Dense 512B store instrs: f32x2 index (q<<6)+lane within each 2KB row.
  {
    f32x2* encw = (f32x2*)(out + ENC_OFF) + ((long long)n0 << 8);
    #pragma unroll 4
    for (int r = 0; r < 16; ++r) {
      int rbA = __shfl(biA, r);
      int rbB = __shfl(biB, r);
      f32x2* rowA = encw + (r << 8);
      f32x2* rowB = encw + ((16 + r) << 8);
      #pragma unroll
      for (int q = 0; q < 4; ++q) {
        int ci = ((q << 6) + lane) << 1;
        f32x2 vA, vB;
        vA.x = (rbA == ci)     ? 1.0f : 0.0f;
        vA.y = (rbA == ci + 1) ? 1.0f : 0.0f;
        vB.x = (rbB == ci)     ? 1.0f : 0.0f;
        vB.y = (rbB == ci + 1) ? 1.0f : 0.0f;
        rowA[(q << 6) + lane] = vA;
        rowB[(q << 6) + lane] = vB;
      }
    }
  }

  if (lane < 16) {
    idx[n0 + rl] = (unsigned int)biA;
    atomicAdd(&hcnt[biA], 1u);
  } else if (lane < 32) {
    idx[n0 + 16 + rl] = (unsigned int)biB;
    atomicAdd(&hcnt[biB], 1u);
  }

  // loss: each point appears 4x across the wave -> sum * 0.25
  float dl = (cnA + scoreA) + (cnB + scoreB);
  #pragma unroll
  for (int off = 1; off < 64; off <<= 1) dl += __shfl_xor(dl, off);
  if (lane == 0) lred[wv] = dl * 0.25f;

  __syncthreads();
  if (tid == 0) {
    float s = 0.0f;
    #pragma unroll
    for (int i = 0; i < 8; ++i) s += lred[i];
    lpart[blockIdx.x] = s;
  }
  unsigned int hv = hcnt[tid];
  if (hv) atomicAdd(&counts[tid], hv);
}

// Quant (contiguous 64KB/block streams) + fused finalizer (block 512).
__global__ __launch_bounds__(256) void vq_write(
    const float* __restrict__ W, const unsigned int* __restrict__ idx,
    const unsigned int* __restrict__ counts, const float* __restrict__ lpart,
    float* __restrict__ out) {
  int bid = blockIdx.x;
  int tid = threadIdx.x;
  if (bid < 512) {
    float* quant = out + QUANT_OFF;
    int e0 = bid << 14;                    // 16384 elems per block
    #pragma unroll 4
    for (int i = 0; i < 64; ++i) {
      int e = e0 + (i << 8) + tid;
      int b = e >> 18, ch = (e >> 12) & 63, hw = e & 4095;
      int n = (b << 12) | hw;
      quant[e] = W[(idx[n] << 6) | ch];
    }
  } else {
    // finalizer: 256 threads cover 512 codes / 512 loss partials
    __shared__ float red[4], red2[4];
    float pr0 = (float)counts[tid]       * (1.0f / 131072.0f);
    float pr1 = (float)counts[tid + 256] * (1.0f / 131072.0f);
    float s = pr0 * logf(pr0 + 1e-10f) + pr1 * logf(pr1 + 1e-10f);
    float l = lpart[tid] + lpart[tid + 256];
    #pragma unroll
    for (int off = 32; off; off >>= 1) {
      s += __shfl_down(s, off, 64);
      l += __shfl_down(l, off, 64);
    }
    if ((tid & 63) == 0) { red[tid >> 6] = s; red2[tid >> 6] = l; }
    __syncthreads();
    if (tid == 0) {
      float H = 0.0f, L = 0.0f;
      #pragma unroll
      for (int i = 0; i < 4; ++i) { H += red[i]; L += red2[i]; }
      out[PERP_OFF] = expf(-H);
      out[0] = 1.25f * L * (1.0f / 8388608.0f);
    }
  }
}

extern "C" void kernel_launch(void* const* d_in, const int* in_sizes, int n_in,
                              void* d_out, int out_size, void* d_ws, size_t ws_size,
                              hipStream_t stream) {
  (void)in_sizes; (void)n_in; (void)out_size; (void)ws_size;
  const float* x = (const float*)d_in[0];
  const float* W = (const float*)d_in[1];
  float* out = (float*)d_out;

  char* ws = (char*)d_ws;
  unsigned int* counts = (unsigned int*)ws;
  float* sw2           = (float*)(ws + 2048);
  float* lpart         = (float*)(ws + 4096);
  unsigned short* w2   = (unsigned short*)(ws + 8192);
  unsigned int* idx    = (unsigned int*)(ws + 73728);

  vq_prep<<<512, 64, 0, stream>>>(W, sw2, w2, counts);
  vq_argmin<<<512, 512, 0, stream>>>(x, w2, sw2, idx, counts, lpart, out);
  vq_write<<<513, 256, 0, stream>>>(W, idx, counts, lpart, out);
}